// Round 9
// baseline (518.226 us; speedup 1.0000x reference)
//
#include <hip/hip_runtime.h>
#include <stdint.h>
#include <stddef.h>

#define B_ 4
#define S_ 2048
#define D_ 1024
#define H_ 16
#define DK_ 64
#define M_ (B_*S_)
#define NEGINF (-1e30f)
#define THR_ 8.0f

#if __has_builtin(__builtin_amdgcn_exp2f)
#define EXP2F(x) __builtin_amdgcn_exp2f(x)
#else
#define EXP2F(x) exp2f(x)
#endif

typedef _Float16 f16;
typedef __attribute__((ext_vector_type(8))) _Float16 f16x8;
typedef __attribute__((ext_vector_type(4))) _Float16 f16x4;
typedef __attribute__((ext_vector_type(4))) float f32x4;

// async global->LDS, 16B per lane; LDS dest = wave-uniform base + lane*16
__device__ __forceinline__ void gload16(const void* g, void* l) {
  __builtin_amdgcn_global_load_lds(
      (const __attribute__((address_space(1))) uint32_t*)g,
      (__attribute__((address_space(3))) uint32_t*)l, 16, 0, 0);
}

// ---------------- convert src f32 -> f16 ----------------
__global__ void k_cvt_src(const float* __restrict__ in, f16* __restrict__ out) {
  int i = blockIdx.x*256 + threadIdx.x;
  const f32x4* p = (const f32x4*)in;
  f32x4 a = p[2*i], b = p[2*i+1];
  f16x8 o;
  o[0]=(f16)a[0]; o[1]=(f16)a[1]; o[2]=(f16)a[2]; o[3]=(f16)a[3];
  o[4]=(f16)b[0]; o[5]=(f16)b[1]; o[6]=(f16)b[2]; o[7]=(f16)b[3];
  ((f16x8*)out)[i] = o;
}

// ---------------- convert + transpose all 4 weights: W[k][n] -> Wt[n][k] f16 ----------------
__global__ void k_cvt_wt(const float* __restrict__ W0, const float* __restrict__ W1,
                         const float* __restrict__ W2, const float* __restrict__ W3,
                         f16* __restrict__ WtBase) {
  __shared__ float tile[64][65];
  const float* W = (blockIdx.z==0) ? W0 : (blockIdx.z==1) ? W1 : (blockIdx.z==2) ? W2 : W3;
  f16* Wt = WtBase + (size_t)blockIdx.z*D_*D_;
  int k0 = blockIdx.x*64, n0 = blockIdx.y*64;
  int t = threadIdx.x;
  int c4 = t & 15, r0 = t >> 4;
  #pragma unroll
  for (int i = 0; i < 4; i++) {
    int r = r0 + i*16;
    f32x4 v = *(const f32x4*)&W[(size_t)(k0 + r)*D_ + n0 + c4*4];
    tile[r][c4*4+0]=v[0]; tile[r][c4*4+1]=v[1]; tile[r][c4*4+2]=v[2]; tile[r][c4*4+3]=v[3];
  }
  __syncthreads();
  #pragma unroll
  for (int i = 0; i < 4; i++) {
    int nr = r0 + i*16;
    int kc = c4*4;
    f16x4 o;
    o[0]=(f16)tile[kc+0][nr]; o[1]=(f16)tile[kc+1][nr];
    o[2]=(f16)tile[kc+2][nr]; o[3]=(f16)tile[kc+3][nr];
    *(f16x4*)&Wt[(size_t)(n0+nr)*D_ + k0 + kc] = o;
  }
}

// ---------------- both bool(int32) masks -> bitmask words (one launch) ----------------
__global__ void k_masks(const int* __restrict__ am, const int* __restrict__ kp,
                        uint32_t* __restrict__ amw, uint32_t* __restrict__ kpw) {
  int g = blockIdx.x*4 + (threadIdx.x>>6);
  int lane = threadIdx.x & 63;
  const int NAM = S_*S_/64;
  int v; uint32_t* dst;
  if (g < NAM) { v = am[(size_t)g*64 + lane]; dst = amw + (size_t)g*2; }
  else         { int g2 = g - NAM; v = kp[(size_t)g2*64 + lane]; dst = kpw + (size_t)g2*2; }
  unsigned long long bal = __ballot(v != 0);
  if (lane == 0) { dst[0] = (uint32_t)bal; dst[1] = (uint32_t)(bal>>32); }
}

// ---------------- fused QKV GEMM (m97 structure), z selects projection ----------------
// z=0: Q out f16 scaled by 0.125*log2(e).  z=1: K out f16.  z=2: V -> Vt[bh][dk][s].
__global__ __launch_bounds__(256, 2) void k_gemm_qkv(
    const f16* __restrict__ A, const f16* __restrict__ WtBase,
    const float* __restrict__ bq, const float* __restrict__ bk, const float* __restrict__ bv,
    f16* __restrict__ Qh, f16* __restrict__ Kh, f16* __restrict__ VtO) {
  __shared__ f16 As[128][64];
  __shared__ f16 Bs[128][64];
  const int z = blockIdx.z;
  const f16* Wt = WtBase + (size_t)z*D_*D_;
  const float* bias = (z==0) ? bq : (z==1) ? bk : bv;
  const int t = threadIdx.x;
  const int wave = t>>6, lane = t&63;
  const int lr = lane&15, lg = lane>>4;
  const int wr = wave>>1, wc = wave&1;
  const int m0 = blockIdx.y*128, n0 = blockIdx.x*128;
  const int srow = lane>>3, scol = (lane&7)*8;

  const f16* ga = A  + (size_t)m0*D_;
  const f16* gb = Wt + (size_t)n0*D_;

  f32x4 acc[4][4] = {};
  for (int kk=0; kk<16; kk++) {
    __syncthreads();
    #pragma unroll
    for (int i=0;i<4;i++){
      int rbase = i*32 + wave*8;
      gload16(&ga[(size_t)(rbase+srow)*D_ + kk*64 + scol], &As[rbase][0]);
      gload16(&gb[(size_t)(rbase+srow)*D_ + kk*64 + scol], &Bs[rbase][0]);
    }
    __syncthreads();
    #pragma unroll
    for (int s=0;s<2;s++) {
      f16x8 af[4], bf[4];
      #pragma unroll
      for (int i=0;i<4;i++) af[i] = *(const f16x8*)&As[wr*64 + i*16 + lr][s*32 + lg*8];
      #pragma unroll
      for (int i=0;i<4;i++) bf[i] = *(const f16x8*)&Bs[wc*64 + i*16 + lr][s*32 + lg*8];
      #pragma unroll
      for (int i=0;i<4;i++)
        #pragma unroll
        for (int j=0;j<4;j++)
          acc[i][j] = __builtin_amdgcn_mfma_f32_16x16x32_f16(af[i], bf[j], acc[i][j],0,0,0);
    }
  }
  #pragma unroll
  for (int fn=0; fn<4; fn++) {
    int n = n0 + wc*64 + fn*16 + lr;
    float bvv = bias[n];
    #pragma unroll
    for (int fm=0; fm<4; fm++) {
      int mrow = m0 + wr*64 + fm*16 + lg*4;
      if (z == 0) {
        #pragma unroll
        for (int j=0;j<4;j++) Qh[(size_t)(mrow+j)*D_ + n] = (f16)((acc[fm][fn][j] + bvv)*0.1803368801111204f);
      } else if (z == 1) {
        #pragma unroll
        for (int j=0;j<4;j++) Kh[(size_t)(mrow+j)*D_ + n] = (f16)(acc[fm][fn][j] + bvv);
      } else {
        int hh = n >> 6, dk = n & 63;
        int bb = mrow >> 11, ss = mrow & (S_-1);
        f16x4 o;
        #pragma unroll
        for (int j=0;j<4;j++) o[j] = (f16)(acc[fm][fn][j] + bvv);
        *(f16x4*)&VtO[((size_t)(bb*H_ + hh)*DK_ + dk)*S_ + ss] = o;
      }
    }
  }
}

// ---------------- output GEMM: f32 out ----------------
__global__ __launch_bounds__(256, 2) void k_gemm_o(
    const f16* __restrict__ A, const f16* __restrict__ Wt,
    const float* __restrict__ bias, float* __restrict__ O) {
  __shared__ f16 As[128][64];
  __shared__ f16 Bs[128][64];
  const int t = threadIdx.x;
  const int wave = t>>6, lane = t&63;
  const int lr = lane&15, lg = lane>>4;
  const int wr = wave>>1, wc = wave&1;
  const int m0 = blockIdx.y*128, n0 = blockIdx.x*128;
  const int srow = lane>>3, scol = (lane&7)*8;

  const f16* ga = A  + (size_t)m0*D_;
  const f16* gb = Wt + (size_t)n0*D_;

  f32x4 acc[4][4] = {};
  for (int kk=0; kk<16; kk++) {
    __syncthreads();
    #pragma unroll
    for (int i=0;i<4;i++){
      int rbase = i*32 + wave*8;
      gload16(&ga[(size_t)(rbase+srow)*D_ + kk*64 + scol], &As[rbase][0]);
      gload16(&gb[(size_t)(rbase+srow)*D_ + kk*64 + scol], &Bs[rbase][0]);
    }
    __syncthreads();
    #pragma unroll
    for (int s=0;s<2;s++) {
      f16x8 af[4], bf[4];
      #pragma unroll
      for (int i=0;i<4;i++) af[i] = *(const f16x8*)&As[wr*64 + i*16 + lr][s*32 + lg*8];
      #pragma unroll
      for (int i=0;i<4;i++) bf[i] = *(const f16x8*)&Bs[wc*64 + i*16 + lr][s*32 + lg*8];
      #pragma unroll
      for (int i=0;i<4;i++)
        #pragma unroll
        for (int j=0;j<4;j++)
          acc[i][j] = __builtin_amdgcn_mfma_f32_16x16x32_f16(af[i], bf[j], acc[i][j],0,0,0);
    }
  }
  #pragma unroll
  for (int fn=0; fn<4; fn++) {
    int n = n0 + wc*64 + fn*16 + lr;
    float bv = bias[n];
    #pragma unroll
    for (int fm=0; fm<4; fm++) {
      int mrow = m0 + wr*64 + fm*16 + lg*4;
      #pragma unroll
      for (int j=0;j<4;j++) O[(size_t)(mrow+j)*D_ + n] = acc[fm][fn][j] + bv;
    }
  }
}

// ---------------- single-pass flash: context + per-row stats ----------------
// K staged in LDS (4-wave reuse, key-permuted rows); V fragments loaded DIRECTLY
// from L2-resident Vt (no cross-lane reuse -> LDS staging is pure overhead).
// va loads issued before QK^T so L2 latency hides under MFMA+softmax.
__global__ __launch_bounds__(256, 2) void k_flash(
    const f16* __restrict__ Qh, const f16* __restrict__ Kh, const f16* __restrict__ Vt,
    const uint32_t* __restrict__ amw, const uint32_t* __restrict__ kpw,
    float2* __restrict__ stats, f16* __restrict__ ctx) {
  __shared__ f16 Kt[64][72];
  __shared__ f16 Pl[4][32][72];
  __shared__ float ssc[4][2][16];

  const int t = threadIdx.x, wave = t>>6, lane = t&63;
  const int lr = lane&15, lg = lane>>4;
  const int sh4 = 4*lr;
  const int flat = blockIdx.x;
  const int vid = (flat & 7)*128 + (flat >> 3);   // XCD swizzle: 8 bh per XCD
  const int bh = vid >> 4, qt = vid & 15;
  const int b = bh >> 4, h = bh & 15;
  const int qb = qt*128 + wave*32;

  const f16* kbase = Kh + (size_t)b*S_*D_ + h*64;
  const f16* vbase = Vt + (size_t)bh*DK_*S_;

  f16x8 qf[2][2];
  #pragma unroll
  for (int qi=0; qi<2; qi++)
    #pragma unroll
    for (int s=0; s<2; s++)
      qf[qi][s] = *(const f16x8*)&Qh[(size_t)(b*S_ + qb + qi*16 + lr)*D_ + h*64 + s*32 + lg*8];

  const int rA = t>>3, cA = t&7;
  const int rB = 32 + (t>>3);
  const int vA = ((rA&3)<<4) | (rA>>2);
  const int vB = ((rB&3)<<4) | (rB>>2);

  float mu[2][4], mg[2][4], l_[2][4];
  #pragma unroll
  for (int qi=0;qi<2;qi++)
    #pragma unroll
    for (int j=0;j<4;j++){ mu[qi][j]=NEGINF; mg[qi][j]=0.f; l_[qi][j]=0.f; }
  f32x4 ct[4][2] = {};

  f16x8 sk0 = *(const f16x8*)&kbase[(size_t)rA*D_ + cA*8];
  f16x8 sk1 = *(const f16x8*)&kbase[(size_t)rB*D_ + cA*8];

  for (int kt=0; kt<32; kt++) {
    __syncthreads();
    *(f16x8*)&Kt[vA][cA*8]  = sk0;  *(f16x8*)&Kt[vB][cA*8]  = sk1;
    __syncthreads();
    // V fragments direct from L2 (issued early; consumed after softmax)
    f16x8 va[4][2];
    #pragma unroll
    for (int mf=0; mf<4; mf++)
      #pragma unroll
      for (int s=0; s<2; s++)
        va[mf][s] = *(const f16x8*)&vbase[(size_t)(mf*16 + lr)*S_ + kt*64 + s*32 + lg*8];
    if (kt < 31) {
      sk0 = *(const f16x8*)&kbase[(size_t)((kt+1)*64 + rA)*D_ + cA*8];
      sk1 = *(const f16x8*)&kbase[(size_t)((kt+1)*64 + rB)*D_ + cA*8];
    }
    f32x4 sf[2][4] = {};
    #pragma unroll
    for (int s=0;s<2;s++)
      #pragma unroll
      for (int f=0;f<4;f++) {
        f16x8 kf = *(const f16x8*)&Kt[f*16 + lr][s*32 + lg*8];
        #pragma unroll
        for (int qi=0;qi<2;qi++)
          sf[qi][f] = __builtin_amdgcn_mfma_f32_16x16x32_f16(qf[qi][s], kf, sf[qi][f],0,0,0);
      }
    uint32_t kw0 = kpw[b*64 + kt*2], kw1 = kpw[b*64 + kt*2 + 1];
    int nib[2][4]; float tmx[2][4]; int need = 0;
    #pragma unroll
    for (int qi=0;qi<2;qi++)
      #pragma unroll
      for (int j=0;j<4;j++) {
        int qrow = qb + qi*16 + lg*4 + j;
        uint32_t a0 = amw[(size_t)qrow*64 + kt*2]     | kw0;
        uint32_t a1 = amw[(size_t)qrow*64 + kt*2 + 1] | kw1;
        int nb = (int)((((uint64_t)a1<<32) | a0) >> sh4) & 15;
        nib[qi][j] = nb;
        float x0 = (nb&1) ? NEGINF : sf[qi][0][j];
        float x1 = (nb&2) ? NEGINF : sf[qi][1][j];
        float x2 = (nb&4) ? NEGINF : sf[qi][2][j];
        float x3 = (nb&8) ? NEGINF : sf[qi][3][j];
        float tm = fmaxf(fmaxf(x0,x1), fmaxf(x2,x3));
        tmx[qi][j] = tm;
        need |= (tm > mu[qi][j] + THR_) ? 1 : 0;
      }
    if (__any(need)) {   // rare wave-uniform rescale
      #pragma unroll
      for (int qi=0;qi<2;qi++)
        #pragma unroll
        for (int j=0;j<4;j++) {
          float gm = tmx[qi][j];
          #pragma unroll
          for (int d=1; d<16; d<<=1) gm = fmaxf(gm, __shfl_xor(gm, d));
          float mnew = fmaxf(mu[qi][j], gm);
          float mgn = (mnew <= NEGINF) ? 0.f : mnew;
          float sc = EXP2F(mg[qi][j] - mgn);
          l_[qi][j] *= sc;
          mu[qi][j] = mnew; mg[qi][j] = mgn;
          if (lr == 0) ssc[wave][qi][lg*4+j] = sc;
        }
      asm volatile("s_waitcnt lgkmcnt(0)" ::: "memory");
      __builtin_amdgcn_sched_barrier(0);
      float sv_0 = ssc[wave][0][lr], sv_1 = ssc[wave][1][lr];
      #pragma unroll
      for (int mf=0; mf<4; mf++)
        #pragma unroll
        for (int c=0;c<4;c++) { ct[mf][0][c] *= sv_0; ct[mf][1][c] *= sv_1; }
    }
    #pragma unroll
    for (int qi=0;qi<2;qi++)
      #pragma unroll
      for (int j=0;j<4;j++) {
        int nb = nib[qi][j];
        float x0 = (nb&1) ? NEGINF : sf[qi][0][j];
        float x1 = (nb&2) ? NEGINF : sf[qi][1][j];
        float x2 = (nb&4) ? NEGINF : sf[qi][2][j];
        float x3 = (nb&8) ? NEGINF : sf[qi][3][j];
        float e0 = EXP2F(x0 - mg[qi][j]);
        float e1 = EXP2F(x1 - mg[qi][j]);
        float e2 = EXP2F(x2 - mg[qi][j]);
        float e3 = EXP2F(x3 - mg[qi][j]);
        l_[qi][j] += (e0+e1)+(e2+e3);
        f16x4 pv4; pv4[0]=(f16)e0; pv4[1]=(f16)e1; pv4[2]=(f16)e2; pv4[3]=(f16)e3;
        *(f16x4*)&Pl[wave][qi*16 + lg*4 + j][sh4] = pv4;
      }
    #pragma unroll
    for (int s=0;s<2;s++) {
      f16x8 pb0 = *(const f16x8*)&Pl[wave][lr][s*32 + lg*8];
      f16x8 pb1 = *(const f16x8*)&Pl[wave][16 + lr][s*32 + lg*8];
      #pragma unroll
      for (int mf=0; mf<4; mf++) {
        ct[mf][0] = __builtin_amdgcn_mfma_f32_16x16x32_f16(va[mf][s], pb0, ct[mf][0],0,0,0);
        ct[mf][1] = __builtin_amdgcn_mfma_f32_16x16x32_f16(va[mf][s], pb1, ct[mf][1],0,0,0);
      }
    }
  }

  // merge per-lane l across the 16-lane group; publish stats; normalize context
  #pragma unroll
  for (int qi=0;qi<2;qi++)
    #pragma unroll
    for (int j=0;j<4;j++) {
      float ls = l_[qi][j];
      #pragma unroll
      for (int d=1; d<16; d<<=1) ls += __shfl_xor(ls, d);
      float ilv = (ls > 0.f) ? 1.f/ls : 0.f;
      if (lr == 0) {
        ssc[wave][qi][lg*4+j] = ilv;
        stats[(size_t)bh*S_ + qb + qi*16 + lg*4 + j] = make_float2(mg[qi][j], ilv);
      }
    }
  asm volatile("s_waitcnt lgkmcnt(0)" ::: "memory");
  __builtin_amdgcn_sched_barrier(0);
  float il0 = ssc[wave][0][lr], il1 = ssc[wave][1][lr];

  // ct[mf][qi]: row dk = mf*16+lg*4+j, col q = qi*16+lr  ->  bounce to [q][dk]
  #pragma unroll
  for (int mf=0; mf<4; mf++)
    #pragma unroll
    for (int qi=0; qi<2; qi++) {
      float ilc = qi ? il1 : il0;
      f16x4 o;
      #pragma unroll
      for (int j=0;j<4;j++) o[j] = (f16)(ct[mf][qi][j] * ilc);
      *(f16x4*)&Pl[wave][qi*16 + lr][mf*16 + lg*4] = o;
    }
  __builtin_amdgcn_s_waitcnt(0);
  #pragma unroll
  for (int i=0;i<4;i++) {
    int idx = i*64 + lane;
    int row = idx >> 3, ch = idx & 7;
    f16x8 o = *(const f16x8*)&Pl[wave][row][ch*8];
    *(f16x8*)&ctx[(size_t)(b*S_ + qb + row)*D_ + h*64 + ch*8] = o;
  }
}

// ---------------- attn writer: one-shot 128x128 score tile, nontemporal streaming stores ----------------
__global__ __launch_bounds__(256, 2) void k_attnw(
    const f16* __restrict__ Qh, const f16* __restrict__ Kh,
    const uint32_t* __restrict__ amw, const uint32_t* __restrict__ kpw,
    const float2* __restrict__ stats, float* __restrict__ attnp) {
  __shared__ f16 Ks[128][72];   // key-permuted within each 64-half
  const int t = threadIdx.x, wave = t>>6, lane = t&63;
  const int lr = lane&15, lg = lane>>4;
  const int sh4 = 4*lr;
  const int ktb = blockIdx.x, qt = blockIdx.y, bh = blockIdx.z;
  const int b = bh >> 4, h = bh & 15;
  const int qb = qt*128, kb = ktb*128;

  #pragma unroll
  for (int i=0;i<4;i++) {
    int q = i*256 + t;
    int r = q>>3, c = q&7;
    int half = r>>6, rr = r&63;
    int v = ((rr&3)<<4) | (rr>>2);
    *(f16x8*)&Ks[half*64 + v][c*8] =
        *(const f16x8*)&Kh[(size_t)(b*S_ + kb + r)*D_ + h*64 + c*8];
  }
  f16x8 qf[2][2];
  #pragma unroll
  for (int qi=0; qi<2; qi++)
    #pragma unroll
    for (int s=0; s<2; s++)
      qf[qi][s] = *(const f16x8*)&Qh[(size_t)(b*S_ + qb + wave*32 + qi*16 + lr)*D_ + h*64 + s*32 + lg*8];
  __syncthreads();   // only barrier in the kernel

  f32x4 sf[2][8] = {};
  #pragma unroll
  for (int s=0;s<2;s++)
    #pragma unroll
    for (int f=0;f<8;f++) {
      f16x8 kf = *(const f16x8*)&Ks[f*16 + lr][s*32 + lg*8];
      #pragma unroll
      for (int qi=0;qi<2;qi++)
        sf[qi][f] = __builtin_amdgcn_mfma_f32_16x16x32_f16(qf[qi][s], kf, sf[qi][f],0,0,0);
    }

  uint32_t kw[4];
  #pragma unroll
  for (int i=0;i<4;i++) kw[i] = kpw[b*64 + ktb*4 + i];

  #pragma unroll
  for (int qi=0;qi<2;qi++)
    #pragma unroll
    for (int j=0;j<4;j++) {
      int qrow = qb + wave*32 + qi*16 + lg*4 + j;
      float2 st = stats[(size_t)bh*S_ + qrow];
      #pragma unroll
      for (int half=0; half<2; half++) {
        uint32_t a0 = amw[(size_t)qrow*64 + ktb*4 + half*2]     | kw[half*2];
        uint32_t a1 = amw[(size_t)qrow*64 + ktb*4 + half*2 + 1] | kw[half*2+1];
        int nb = (int)((((uint64_t)a1<<32) | a0) >> sh4) & 15;
        float x0 = (nb&1) ? NEGINF : sf[qi][half*4+0][j];
        float x1 = (nb&2) ? NEGINF : sf[qi][half*4+1][j];
        float x2 = (nb&4) ? NEGINF : sf[qi][half*4+2][j];
        float x3 = (nb&8) ? NEGINF : sf[qi][half*4+3][j];
        f32x4 ev;
        ev[0] = EXP2F(x0 - st.x) * st.y;
        ev[1] = EXP2F(x1 - st.x) * st.y;
        ev[2] = EXP2F(x2 - st.x) * st.y;
        ev[3] = EXP2F(x3 - st.x) * st.y;
        __builtin_nontemporal_store(ev,
            (f32x4*)&attnp[((size_t)bh*S_ + qrow)*S_ + kb + half*64 + sh4]);
      }
    }
}

// ---------------- launch ----------------
extern "C" void kernel_launch(void* const* d_in, const int* in_sizes, int n_in,
                              void* d_out, int out_size, void* d_ws, size_t ws_size,
                              hipStream_t stream) {
  const float* src = (const float*)d_in[0];
  const int*   am  = (const int*)d_in[1];
  const int*   kp  = (const int*)d_in[2];
  const float* Wq  = (const float*)d_in[3];
  const float* bq  = (const float*)d_in[4];
  const float* Wk  = (const float*)d_in[5];
  const float* bk  = (const float*)d_in[6];
  const float* Wv  = (const float*)d_in[7];
  const float* bv  = (const float*)d_in[8];
  const float* Wo  = (const float*)d_in[9];
  const float* bo  = (const float*)d_in[10];

  const size_t need = (size_t)M_*D_*2        // Xh
                    + (size_t)4*D_*D_*2      // Wth
                    + (size_t)4*M_*D_*2      // Qh,Kh,Vt,CT
                    + (size_t)S_*S_/8        // amw
                    + (size_t)B_*S_/8        // kpw
                    + (size_t)M_*8;          // stats
  if (ws_size < need) return;

  char* w = (char*)d_ws;
  f16* Xh  = (f16*)w;  w += (size_t)M_*D_*2;
  f16* Wth = (f16*)w;  w += (size_t)4*D_*D_*2;
  f16* Qh  = (f16*)w;  w += (size_t)M_*D_*2;
  f16* Kh  = (f16*)w;  w += (size_t)M_*D_*2;
  f16* Vt  = (f16*)w;  w += (size_t)M_*D_*2;
  f16* CT  = (f16*)w;  w += (size_t)M_*D_*2;
  uint32_t* amw = (uint32_t*)w; w += (size_t)S_*S_/8;
  uint32_t* kpw = (uint32_t*)w; w += (size_t)B_*S_/8;
  float2* stats = (float2*)w;

  float* outp  = (float*)d_out;
  float* attnp = outp + (size_t)M_*D_;

  k_cvt_src<<<M_*D_/8/256, 256, 0, stream>>>(src, Xh);
  k_cvt_wt<<<dim3(16,16,4), 256, 0, stream>>>(Wq, Wk, Wv, Wo, Wth);
  k_masks<<<(S_*S_/64 + B_*S_/64)/4, 256, 0, stream>>>(am, kp, amw, kpw);
  k_gemm_qkv<<<dim3(8,64,3), 256, 0, stream>>>(Xh, Wth, bq, bk, bv, Qh, Kh, Vt);
  k_flash<<<1024, 256, 0, stream>>>(Qh, Kh, Vt, amw, kpw, stats, CT);
  k_gemm_o<<<dim3(8,64), 256, 0, stream>>>(CT, Wth + 3*(size_t)D_*D_, bo, outp);
  k_attnw<<<dim3(16,16,64), 256, 0, stream>>>(Qh, Kh, amw, kpw, stats, attnp);
}

// Round 10
// 450.760 us; speedup vs baseline: 1.1497x; 1.1497x over previous
//
#include <hip/hip_runtime.h>
#include <stdint.h>
#include <stddef.h>

#define B_ 4
#define S_ 2048
#define D_ 1024
#define H_ 16
#define DK_ 64
#define M_ (B_*S_)
#define NEGINF (-1e30f)
#define THR_ 8.0f

#if __has_builtin(__builtin_amdgcn_exp2f)
#define EXP2F(x) __builtin_amdgcn_exp2f(x)
#else
#define EXP2F(x) exp2f(x)
#endif

typedef _Float16 f16;
typedef __attribute__((ext_vector_type(8))) _Float16 f16x8;
typedef __attribute__((ext_vector_type(4))) _Float16 f16x4;
typedef __attribute__((ext_vector_type(4))) float f32x4;

// async global->LDS, 16B per lane; LDS dest = wave-uniform base + lane*16
__device__ __forceinline__ void gload16(const void* g, void* l) {
  __builtin_amdgcn_global_load_lds(
      (const __attribute__((address_space(1))) uint32_t*)g,
      (__attribute__((address_space(3))) uint32_t*)l, 16, 0, 0);
}

// ---------------- convert src f32 -> f16 ----------------
__global__ void k_cvt_src(const float* __restrict__ in, f16* __restrict__ out) {
  int i = blockIdx.x*256 + threadIdx.x;
  const f32x4* p = (const f32x4*)in;
  f32x4 a = p[2*i], b = p[2*i+1];
  f16x8 o;
  o[0]=(f16)a[0]; o[1]=(f16)a[1]; o[2]=(f16)a[2]; o[3]=(f16)a[3];
  o[4]=(f16)b[0]; o[5]=(f16)b[1]; o[6]=(f16)b[2]; o[7]=(f16)b[3];
  ((f16x8*)out)[i] = o;
}

// ---------------- convert + transpose all 4 weights: W[k][n] -> Wt[n][k] f16 ----------------
__global__ void k_cvt_wt(const float* __restrict__ W0, const float* __restrict__ W1,
                         const float* __restrict__ W2, const float* __restrict__ W3,
                         f16* __restrict__ WtBase) {
  __shared__ float tile[64][65];
  const float* W = (blockIdx.z==0) ? W0 : (blockIdx.z==1) ? W1 : (blockIdx.z==2) ? W2 : W3;
  f16* Wt = WtBase + (size_t)blockIdx.z*D_*D_;
  int k0 = blockIdx.x*64, n0 = blockIdx.y*64;
  int t = threadIdx.x;
  int c4 = t & 15, r0 = t >> 4;
  #pragma unroll
  for (int i = 0; i < 4; i++) {
    int r = r0 + i*16;
    f32x4 v = *(const f32x4*)&W[(size_t)(k0 + r)*D_ + n0 + c4*4];
    tile[r][c4*4+0]=v[0]; tile[r][c4*4+1]=v[1]; tile[r][c4*4+2]=v[2]; tile[r][c4*4+3]=v[3];
  }
  __syncthreads();
  #pragma unroll
  for (int i = 0; i < 4; i++) {
    int nr = r0 + i*16;
    int kc = c4*4;
    f16x4 o;
    o[0]=(f16)tile[kc+0][nr]; o[1]=(f16)tile[kc+1][nr];
    o[2]=(f16)tile[kc+2][nr]; o[3]=(f16)tile[kc+3][nr];
    *(f16x4*)&Wt[(size_t)(n0+nr)*D_ + k0 + kc] = o;
  }
}

// ---------------- both bool(int32) masks -> bitmask words (one launch) ----------------
__global__ void k_masks(const int* __restrict__ am, const int* __restrict__ kp,
                        uint32_t* __restrict__ amw, uint32_t* __restrict__ kpw) {
  int g = blockIdx.x*4 + (threadIdx.x>>6);
  int lane = threadIdx.x & 63;
  const int NAM = S_*S_/64;
  int v; uint32_t* dst;
  if (g < NAM) { v = am[(size_t)g*64 + lane]; dst = amw + (size_t)g*2; }
  else         { int g2 = g - NAM; v = kp[(size_t)g2*64 + lane]; dst = kpw + (size_t)g2*2; }
  unsigned long long bal = __ballot(v != 0);
  if (lane == 0) { dst[0] = (uint32_t)bal; dst[1] = (uint32_t)(bal>>32); }
}

// ---------------- fused QKV GEMM (m97 structure), z selects projection ----------------
// z=0: Q out f16 scaled by 0.125*log2(e).  z=1: K out f16.  z=2: V -> Vt[bh][dk][s].
__global__ __launch_bounds__(256, 2) void k_gemm_qkv(
    const f16* __restrict__ A, const f16* __restrict__ WtBase,
    const float* __restrict__ bq, const float* __restrict__ bk, const float* __restrict__ bv,
    f16* __restrict__ Qh, f16* __restrict__ Kh, f16* __restrict__ VtO) {
  __shared__ f16 As[128][64];
  __shared__ f16 Bs[128][64];
  const int z = blockIdx.z;
  const f16* Wt = WtBase + (size_t)z*D_*D_;
  const float* bias = (z==0) ? bq : (z==1) ? bk : bv;
  const int t = threadIdx.x;
  const int wave = t>>6, lane = t&63;
  const int lr = lane&15, lg = lane>>4;
  const int wr = wave>>1, wc = wave&1;
  const int m0 = blockIdx.y*128, n0 = blockIdx.x*128;
  const int srow = lane>>3, scol = (lane&7)*8;

  const f16* ga = A  + (size_t)m0*D_;
  const f16* gb = Wt + (size_t)n0*D_;

  f32x4 acc[4][4] = {};
  for (int kk=0; kk<16; kk++) {
    __syncthreads();
    #pragma unroll
    for (int i=0;i<4;i++){
      int rbase = i*32 + wave*8;
      gload16(&ga[(size_t)(rbase+srow)*D_ + kk*64 + scol], &As[rbase][0]);
      gload16(&gb[(size_t)(rbase+srow)*D_ + kk*64 + scol], &Bs[rbase][0]);
    }
    __syncthreads();
    #pragma unroll
    for (int s=0;s<2;s++) {
      f16x8 af[4], bf[4];
      #pragma unroll
      for (int i=0;i<4;i++) af[i] = *(const f16x8*)&As[wr*64 + i*16 + lr][s*32 + lg*8];
      #pragma unroll
      for (int i=0;i<4;i++) bf[i] = *(const f16x8*)&Bs[wc*64 + i*16 + lr][s*32 + lg*8];
      #pragma unroll
      for (int i=0;i<4;i++)
        #pragma unroll
        for (int j=0;j<4;j++)
          acc[i][j] = __builtin_amdgcn_mfma_f32_16x16x32_f16(af[i], bf[j], acc[i][j],0,0,0);
    }
  }
  #pragma unroll
  for (int fn=0; fn<4; fn++) {
    int n = n0 + wc*64 + fn*16 + lr;
    float bvv = bias[n];
    #pragma unroll
    for (int fm=0; fm<4; fm++) {
      int mrow = m0 + wr*64 + fm*16 + lg*4;
      if (z == 0) {
        #pragma unroll
        for (int j=0;j<4;j++) Qh[(size_t)(mrow+j)*D_ + n] = (f16)((acc[fm][fn][j] + bvv)*0.1803368801111204f);
      } else if (z == 1) {
        #pragma unroll
        for (int j=0;j<4;j++) Kh[(size_t)(mrow+j)*D_ + n] = (f16)(acc[fm][fn][j] + bvv);
      } else {
        int hh = n >> 6, dk = n & 63;
        int bb = mrow >> 11, ss = mrow & (S_-1);
        f16x4 o;
        #pragma unroll
        for (int j=0;j<4;j++) o[j] = (f16)(acc[fm][fn][j] + bvv);
        *(f16x4*)&VtO[((size_t)(bb*H_ + hh)*DK_ + dk)*S_ + ss] = o;
      }
    }
  }
}

// ---------------- output GEMM: f32 out ----------------
__global__ __launch_bounds__(256, 2) void k_gemm_o(
    const f16* __restrict__ A, const f16* __restrict__ Wt,
    const float* __restrict__ bias, float* __restrict__ O) {
  __shared__ f16 As[128][64];
  __shared__ f16 Bs[128][64];
  const int t = threadIdx.x;
  const int wave = t>>6, lane = t&63;
  const int lr = lane&15, lg = lane>>4;
  const int wr = wave>>1, wc = wave&1;
  const int m0 = blockIdx.y*128, n0 = blockIdx.x*128;
  const int srow = lane>>3, scol = (lane&7)*8;

  const f16* ga = A  + (size_t)m0*D_;
  const f16* gb = Wt + (size_t)n0*D_;

  f32x4 acc[4][4] = {};
  for (int kk=0; kk<16; kk++) {
    __syncthreads();
    #pragma unroll
    for (int i=0;i<4;i++){
      int rbase = i*32 + wave*8;
      gload16(&ga[(size_t)(rbase+srow)*D_ + kk*64 + scol], &As[rbase][0]);
      gload16(&gb[(size_t)(rbase+srow)*D_ + kk*64 + scol], &Bs[rbase][0]);
    }
    __syncthreads();
    #pragma unroll
    for (int s=0;s<2;s++) {
      f16x8 af[4], bf[4];
      #pragma unroll
      for (int i=0;i<4;i++) af[i] = *(const f16x8*)&As[wr*64 + i*16 + lr][s*32 + lg*8];
      #pragma unroll
      for (int i=0;i<4;i++) bf[i] = *(const f16x8*)&Bs[wc*64 + i*16 + lr][s*32 + lg*8];
      #pragma unroll
      for (int i=0;i<4;i++)
        #pragma unroll
        for (int j=0;j<4;j++)
          acc[i][j] = __builtin_amdgcn_mfma_f32_16x16x32_f16(af[i], bf[j], acc[i][j],0,0,0);
    }
  }
  #pragma unroll
  for (int fn=0; fn<4; fn++) {
    int n = n0 + wc*64 + fn*16 + lr;
    float bv = bias[n];
    #pragma unroll
    for (int fm=0; fm<4; fm++) {
      int mrow = m0 + wr*64 + fm*16 + lg*4;
      #pragma unroll
      for (int j=0;j<4;j++) O[(size_t)(mrow+j)*D_ + n] = acc[fm][fn][j] + bv;
    }
  }
}

// ---------------- single-pass flash (Round-8 body): K AND V staged in LDS ----------------
// K LDS key-permuted (virtual row (r&3)*16+(r>>2)): lane's 4 scores = keys 4*lr+f.
// V staged in Vtt[dk][key]: 4-wave cross-wave reuse (direct loads cost 4x L2 traffic — R9 lesson).
// Online softmax with defer-max (THR=8, exp2 domain), wave-uniform running max per row.
__global__ __launch_bounds__(256, 2) void k_flash(
    const f16* __restrict__ Qh, const f16* __restrict__ Kh, const f16* __restrict__ Vt,
    const uint32_t* __restrict__ amw, const uint32_t* __restrict__ kpw,
    float2* __restrict__ stats, f16* __restrict__ ctx) {
  __shared__ f16 Kt[64][72];
  __shared__ f16 Vtt[64][72];
  __shared__ f16 Pl[4][32][72];
  __shared__ float ssc[4][2][16];

  const int t = threadIdx.x, wave = t>>6, lane = t&63;
  const int lr = lane&15, lg = lane>>4;
  const int sh4 = 4*lr;
  const int flat = blockIdx.x;
  const int vid = (flat & 7)*128 + (flat >> 3);   // XCD swizzle: 8 bh per XCD
  const int bh = vid >> 4, qt = vid & 15;
  const int b = bh >> 4, h = bh & 15;
  const int qb = qt*128 + wave*32;

  const f16* kbase = Kh + (size_t)b*S_*D_ + h*64;
  const f16* vbase = Vt + (size_t)bh*DK_*S_;

  f16x8 qf[2][2];
  #pragma unroll
  for (int qi=0; qi<2; qi++)
    #pragma unroll
    for (int s=0; s<2; s++)
      qf[qi][s] = *(const f16x8*)&Qh[(size_t)(b*S_ + qb + qi*16 + lr)*D_ + h*64 + s*32 + lg*8];

  const int rA = t>>3, cA = t&7;
  const int rB = 32 + (t>>3);
  const int vA = ((rA&3)<<4) | (rA>>2);
  const int vB = ((rB&3)<<4) | (rB>>2);

  float mu[2][4], mg[2][4], l_[2][4];
  #pragma unroll
  for (int qi=0;qi<2;qi++)
    #pragma unroll
    for (int j=0;j<4;j++){ mu[qi][j]=NEGINF; mg[qi][j]=0.f; l_[qi][j]=0.f; }
  f32x4 ct[4][2] = {};

  f16x8 sk0 = *(const f16x8*)&kbase[(size_t)rA*D_ + cA*8];
  f16x8 sk1 = *(const f16x8*)&kbase[(size_t)rB*D_ + cA*8];
  f16x8 sv0 = *(const f16x8*)&vbase[(size_t)rA*S_ + cA*8];
  f16x8 sv1 = *(const f16x8*)&vbase[(size_t)rB*S_ + cA*8];

  for (int kt=0; kt<32; kt++) {
    __syncthreads();
    *(f16x8*)&Kt[vA][cA*8]  = sk0;  *(f16x8*)&Kt[vB][cA*8]  = sk1;
    *(f16x8*)&Vtt[rA][cA*8] = sv0;  *(f16x8*)&Vtt[rB][cA*8] = sv1;
    __syncthreads();
    if (kt < 31) {
      sk0 = *(const f16x8*)&kbase[(size_t)((kt+1)*64 + rA)*D_ + cA*8];
      sk1 = *(const f16x8*)&kbase[(size_t)((kt+1)*64 + rB)*D_ + cA*8];
      sv0 = *(const f16x8*)&vbase[(size_t)rA*S_ + (kt+1)*64 + cA*8];
      sv1 = *(const f16x8*)&vbase[(size_t)rB*S_ + (kt+1)*64 + cA*8];
    }
    f32x4 sf[2][4] = {};
    #pragma unroll
    for (int s=0;s<2;s++)
      #pragma unroll
      for (int f=0;f<4;f++) {
        f16x8 kf = *(const f16x8*)&Kt[f*16 + lr][s*32 + lg*8];
        #pragma unroll
        for (int qi=0;qi<2;qi++)
          sf[qi][f] = __builtin_amdgcn_mfma_f32_16x16x32_f16(qf[qi][s], kf, sf[qi][f],0,0,0);
      }
    uint32_t kw0 = kpw[b*64 + kt*2], kw1 = kpw[b*64 + kt*2 + 1];
    int nib[2][4]; float tmx[2][4]; int need = 0;
    #pragma unroll
    for (int qi=0;qi<2;qi++)
      #pragma unroll
      for (int j=0;j<4;j++) {
        int qrow = qb + qi*16 + lg*4 + j;
        uint32_t a0 = amw[(size_t)qrow*64 + kt*2]     | kw0;
        uint32_t a1 = amw[(size_t)qrow*64 + kt*2 + 1] | kw1;
        int nb = (int)((((uint64_t)a1<<32) | a0) >> sh4) & 15;
        nib[qi][j] = nb;
        float x0 = (nb&1) ? NEGINF : sf[qi][0][j];
        float x1 = (nb&2) ? NEGINF : sf[qi][1][j];
        float x2 = (nb&4) ? NEGINF : sf[qi][2][j];
        float x3 = (nb&8) ? NEGINF : sf[qi][3][j];
        float tm = fmaxf(fmaxf(x0,x1), fmaxf(x2,x3));
        tmx[qi][j] = tm;
        need |= (tm > mu[qi][j] + THR_) ? 1 : 0;
      }
    if (__any(need)) {   // rare wave-uniform rescale
      #pragma unroll
      for (int qi=0;qi<2;qi++)
        #pragma unroll
        for (int j=0;j<4;j++) {
          float gm = tmx[qi][j];
          #pragma unroll
          for (int d=1; d<16; d<<=1) gm = fmaxf(gm, __shfl_xor(gm, d));
          float mnew = fmaxf(mu[qi][j], gm);
          float mgn = (mnew <= NEGINF) ? 0.f : mnew;
          float sc = EXP2F(mg[qi][j] - mgn);
          l_[qi][j] *= sc;
          mu[qi][j] = mnew; mg[qi][j] = mgn;
          if (lr == 0) ssc[wave][qi][lg*4+j] = sc;
        }
      asm volatile("s_waitcnt lgkmcnt(0)" ::: "memory");
      __builtin_amdgcn_sched_barrier(0);
      float sv_0 = ssc[wave][0][lr], sv_1 = ssc[wave][1][lr];
      #pragma unroll
      for (int mf=0; mf<4; mf++)
        #pragma unroll
        for (int c=0;c<4;c++) { ct[mf][0][c] *= sv_0; ct[mf][1][c] *= sv_1; }
    }
    #pragma unroll
    for (int qi=0;qi<2;qi++)
      #pragma unroll
      for (int j=0;j<4;j++) {
        int nb = nib[qi][j];
        float x0 = (nb&1) ? NEGINF : sf[qi][0][j];
        float x1 = (nb&2) ? NEGINF : sf[qi][1][j];
        float x2 = (nb&4) ? NEGINF : sf[qi][2][j];
        float x3 = (nb&8) ? NEGINF : sf[qi][3][j];
        float e0 = EXP2F(x0 - mg[qi][j]);
        float e1 = EXP2F(x1 - mg[qi][j]);
        float e2 = EXP2F(x2 - mg[qi][j]);
        float e3 = EXP2F(x3 - mg[qi][j]);
        l_[qi][j] += (e0+e1)+(e2+e3);
        f16x4 pv4; pv4[0]=(f16)e0; pv4[1]=(f16)e1; pv4[2]=(f16)e2; pv4[3]=(f16)e3;
        *(f16x4*)&Pl[wave][qi*16 + lg*4 + j][sh4] = pv4;
      }
    #pragma unroll
    for (int s=0;s<2;s++) {
      f16x8 pb0 = *(const f16x8*)&Pl[wave][lr][s*32 + lg*8];
      f16x8 pb1 = *(const f16x8*)&Pl[wave][16 + lr][s*32 + lg*8];
      #pragma unroll
      for (int mf=0; mf<4; mf++) {
        f16x8 va = *(const f16x8*)&Vtt[mf*16 + lr][s*32 + lg*8];
        ct[mf][0] = __builtin_amdgcn_mfma_f32_16x16x32_f16(va, pb0, ct[mf][0],0,0,0);
        ct[mf][1] = __builtin_amdgcn_mfma_f32_16x16x32_f16(va, pb1, ct[mf][1],0,0,0);
      }
    }
  }

  // merge per-lane l across the 16-lane group; publish stats; normalize context
  #pragma unroll
  for (int qi=0;qi<2;qi++)
    #pragma unroll
    for (int j=0;j<4;j++) {
      float ls = l_[qi][j];
      #pragma unroll
      for (int d=1; d<16; d<<=1) ls += __shfl_xor(ls, d);
      float ilv = (ls > 0.f) ? 1.f/ls : 0.f;
      if (lr == 0) {
        ssc[wave][qi][lg*4+j] = ilv;
        stats[(size_t)bh*S_ + qb + qi*16 + lg*4 + j] = make_float2(mg[qi][j], ilv);
      }
    }
  asm volatile("s_waitcnt lgkmcnt(0)" ::: "memory");
  __builtin_amdgcn_sched_barrier(0);
  float il0 = ssc[wave][0][lr], il1 = ssc[wave][1][lr];

  // ct[mf][qi]: row dk = mf*16+lg*4+j, col q = qi*16+lr  ->  bounce to [q][dk]
  #pragma unroll
  for (int mf=0; mf<4; mf++)
    #pragma unroll
    for (int qi=0; qi<2; qi++) {
      float ilc = qi ? il1 : il0;
      f16x4 o;
      #pragma unroll
      for (int j=0;j<4;j++) o[j] = (f16)(ct[mf][qi][j] * ilc);
      *(f16x4*)&Pl[wave][qi*16 + lr][mf*16 + lg*4] = o;
    }
  __builtin_amdgcn_s_waitcnt(0);
  #pragma unroll
  for (int i=0;i<4;i++) {
    int idx = i*64 + lane;
    int row = idx >> 3, ch = idx & 7;
    f16x8 o = *(const f16x8*)&Pl[wave][row][ch*8];
    *(f16x8*)&ctx[(size_t)(b*S_ + qb + row)*D_ + h*64 + ch*8] = o;
  }
}

// ---------------- attn writer: one-shot 128x128 score tile, nontemporal streaming stores ----------------
__global__ __launch_bounds__(256, 2) void k_attnw(
    const f16* __restrict__ Qh, const f16* __restrict__ Kh,
    const uint32_t* __restrict__ amw, const uint32_t* __restrict__ kpw,
    const float2* __restrict__ stats, float* __restrict__ attnp) {
  __shared__ f16 Ks[128][72];   // key-permuted within each 64-half
  const int t = threadIdx.x, wave = t>>6, lane = t&63;
  const int lr = lane&15, lg = lane>>4;
  const int sh4 = 4*lr;
  const int ktb = blockIdx.x, qt = blockIdx.y, bh = blockIdx.z;
  const int b = bh >> 4, h = bh & 15;
  const int qb = qt*128, kb = ktb*128;

  #pragma unroll
  for (int i=0;i<4;i++) {
    int q = i*256 + t;
    int r = q>>3, c = q&7;
    int half = r>>6, rr = r&63;
    int v = ((rr&3)<<4) | (rr>>2);
    *(f16x8*)&Ks[half*64 + v][c*8] =
        *(const f16x8*)&Kh[(size_t)(b*S_ + kb + r)*D_ + h*64 + c*8];
  }
  f16x8 qf[2][2];
  #pragma unroll
  for (int qi=0; qi<2; qi++)
    #pragma unroll
    for (int s=0; s<2; s++)
      qf[qi][s] = *(const f16x8*)&Qh[(size_t)(b*S_ + qb + wave*32 + qi*16 + lr)*D_ + h*64 + s*32 + lg*8];
  __syncthreads();   // only barrier in the kernel

  f32x4 sf[2][8] = {};
  #pragma unroll
  for (int s=0;s<2;s++)
    #pragma unroll
    for (int f=0;f<8;f++) {
      f16x8 kf = *(const f16x8*)&Ks[f*16 + lr][s*32 + lg*8];
      #pragma unroll
      for (int qi=0;qi<2;qi++)
        sf[qi][f] = __builtin_amdgcn_mfma_f32_16x16x32_f16(qf[qi][s], kf, sf[qi][f],0,0,0);
    }

  uint32_t kw[4];
  #pragma unroll
  for (int i=0;i<4;i++) kw[i] = kpw[b*64 + ktb*4 + i];

  #pragma unroll
  for (int qi=0;qi<2;qi++)
    #pragma unroll
    for (int j=0;j<4;j++) {
      int qrow = qb + wave*32 + qi*16 + lg*4 + j;
      float2 st = stats[(size_t)bh*S_ + qrow];
      #pragma unroll
      for (int half=0; half<2; half++) {
        uint32_t a0 = amw[(size_t)qrow*64 + ktb*4 + half*2]     | kw[half*2];
        uint32_t a1 = amw[(size_t)qrow*64 + ktb*4 + half*2 + 1] | kw[half*2+1];
        int nb = (int)((((uint64_t)a1<<32) | a0) >> sh4) & 15;
        float x0 = (nb&1) ? NEGINF : sf[qi][half*4+0][j];
        float x1 = (nb&2) ? NEGINF : sf[qi][half*4+1][j];
        float x2 = (nb&4) ? NEGINF : sf[qi][half*4+2][j];
        float x3 = (nb&8) ? NEGINF : sf[qi][half*4+3][j];
        f32x4 ev;
        ev[0] = EXP2F(x0 - st.x) * st.y;
        ev[1] = EXP2F(x1 - st.x) * st.y;
        ev[2] = EXP2F(x2 - st.x) * st.y;
        ev[3] = EXP2F(x3 - st.x) * st.y;
        __builtin_nontemporal_store(ev,
            (f32x4*)&attnp[((size_t)bh*S_ + qrow)*S_ + kb + half*64 + sh4]);
      }
    }
}

// ---------------- launch ----------------
extern "C" void kernel_launch(void* const* d_in, const int* in_sizes, int n_in,
                              void* d_out, int out_size, void* d_ws, size_t ws_size,
                              hipStream_t stream) {
  const float* src = (const float*)d_in[0];
  const int*   am  = (const int*)d_in[1];
  const int*   kp  = (const int*)d_in[2];
  const float* Wq  = (const float*)d_in[3];
  const float* bq  = (const float*)d_in[4];
  const float* Wk  = (const float*)d_in[5];
  const float* bk  = (const float*)d_in[6];
  const float* Wv  = (const float*)d_in[7];
  const float* bv  = (const float*)d_in[8];
  const float* Wo  = (const float*)d_in[9];
  const float* bo  = (const float*)d_in[10];

  const size_t need = (size_t)M_*D_*2        // Xh
                    + (size_t)4*D_*D_*2      // Wth
                    + (size_t)4*M_*D_*2      // Qh,Kh,Vt,CT
                    + (size_t)S_*S_/8        // amw
                    + (size_t)B_*S_/8        // kpw
                    + (size_t)M_*8;          // stats
  if (ws_size < need) return;

  char* w = (char*)d_ws;
  f16* Xh  = (f16*)w;  w += (size_t)M_*D_*2;
  f16* Wth = (f16*)w;  w += (size_t)4*D_*D_*2;
  f16* Qh  = (f16*)w;  w += (size_t)M_*D_*2;
  f16* Kh  = (f16*)w;  w += (size_t)M_*D_*2;
  f16* Vt  = (f16*)w;  w += (size_t)M_*D_*2;
  f16* CT  = (f16*)w;  w += (size_t)M_*D_*2;
  uint32_t* amw = (uint32_t*)w; w += (size_t)S_*S_/8;
  uint32_t* kpw = (uint32_t*)w; w += (size_t)B_*S_/8;
  float2* stats = (float2*)w;

  float* outp  = (float*)d_out;
  float* attnp = outp + (size_t)M_*D_;

  k_cvt_src<<<M_*D_/8/256, 256, 0, stream>>>(src, Xh);
  k_cvt_wt<<<dim3(16,16,4), 256, 0, stream>>>(Wq, Wk, Wv, Wo, Wth);
  k_masks<<<(S_*S_/64 + B_*S_/64)/4, 256, 0, stream>>>(am, kp, amw, kpw);
  k_gemm_qkv<<<dim3(8,64,3), 256, 0, stream>>>(Xh, Wth, bq, bk, bv, Qh, Kh, Vt);
  k_flash<<<1024, 256, 0, stream>>>(Qh, Kh, Vt, amw, kpw, stats, CT);
  k_gemm_o<<<dim3(8,64), 256, 0, stream>>>(CT, Wth + 3*(size_t)D_*D_, bo, outp);
  k_attnw<<<dim3(16,16,64), 256, 0, stream>>>(Qh, Kh, amw, kpw, stats, attnp);
}